// Round 1
// baseline (2377.184 us; speedup 1.0000x reference)
//
#include <hip/hip_runtime.h>
#include <math.h>

constexpr int Bn = 8, Cn = 256, Hn = 64, Wn = 64, Fn = 256, Kn = 9;
constexpr int HWn = Hn * Wn;               // 4096
constexpr int NM = Bn * Kn * HWn;          // 294912 meta elements per array
constexpr int CCk = 4;                     // c-channels per K-chunk in dconv

// ---------------- Kernel 1: weight transpose w[f][c*9+k] -> wT[c*9+k][f] ----
__global__ __launch_bounds__(256) void wtrans(const float* __restrict__ wd,
                                              float* __restrict__ wT) {
    int i = blockIdx.x * 256 + threadIdx.x;
    if (i < Fn * Cn * Kn) {
        int f = i / (Cn * Kn);
        int ck = i - f * (Cn * Kn);
        wT[ck * Fn + f] = wd[i];
    }
}

// ---- Kernel 2: offset/mask 3x3 conv (27 ch) + sampling metadata ------------
// meta: midx[corner][b][k][p] clamped flat spatial idx, mwt[corner][...] =
// bilinear weight * sigmoid(mask) * validity.
__global__ __launch_bounds__(128) void offmask(const float* __restrict__ x,
                                               const float* __restrict__ wo,
                                               const float* __restrict__ wm,
                                               int* __restrict__ midx,
                                               float* __restrict__ mwt) {
    __shared__ float xs[8][10][20];        // 8 c, 10 rows (8+halo), 18 cols (pad 20)
    const int tx = threadIdx.x, ty = threadIdx.y;   // block (16,8)
    const int t = ty * 16 + tx;
    const int bx = blockIdx.x, by = blockIdx.y, b = blockIdx.z;
    const int h = by * 8 + ty, w = bx * 16 + tx;

    float acc[27];
#pragma unroll
    for (int i = 0; i < 27; ++i) acc[i] = 0.f;

#pragma unroll 1
    for (int c0 = 0; c0 < Cn; c0 += 8) {
        __syncthreads();
        for (int i = t; i < 8 * 10 * 18; i += 128) {
            int cc = i / 180;
            int rem = i - cc * 180;
            int r = rem / 18;
            int cl = rem - r * 18;
            int gy = by * 8 - 1 + r, gx = bx * 16 - 1 + cl;
            float v = 0.f;
            if (gy >= 0 && gy < Hn && gx >= 0 && gx < Wn)
                v = x[(((b * Cn + c0 + cc) * Hn + gy) << 6) + gx];
            xs[cc][r][cl] = v;
        }
        __syncthreads();
#pragma unroll
        for (int cc = 0; cc < 8; ++cc) {
            float xv[9];
#pragma unroll
            for (int k = 0; k < 9; ++k) xv[k] = xs[cc][ty + k / 3][tx + k % 3];
            const int c = c0 + cc;
#pragma unroll
            for (int oc = 0; oc < 18; ++oc) {
#pragma unroll
                for (int k = 0; k < 9; ++k)
                    acc[oc] = fmaf(xv[k], wo[(oc * Cn + c) * 9 + k], acc[oc]);
            }
#pragma unroll
            for (int oc = 0; oc < 9; ++oc) {
#pragma unroll
                for (int k = 0; k < 9; ++k)
                    acc[18 + oc] = fmaf(xv[k], wm[(oc * Cn + c) * 9 + k], acc[18 + oc]);
            }
        }
    }

    const int p = (h << 6) + w;
#pragma unroll
    for (int k = 0; k < 9; ++k) {
        float dy = acc[2 * k], dx = acc[2 * k + 1];
        float m = 1.f / (1.f + expf(-acc[18 + k]));
        float yy = (float)(h + k / 3 - 1) + dy;
        float xx = (float)(w + k % 3 - 1) + dx;
        float y0f = floorf(yy), x0f = floorf(xx);
        float wy = yy - y0f, wx = xx - x0f;
        int y0 = (int)y0f, x0 = (int)x0f;
        int y1 = y0 + 1, x1 = x0 + 1;
        bool vy0 = (unsigned)y0 < (unsigned)Hn;
        bool vx0 = (unsigned)x0 < (unsigned)Wn;
        bool vy1 = (unsigned)y1 < (unsigned)Hn;
        bool vx1 = (unsigned)x1 < (unsigned)Wn;
        int cy0 = min(max(y0, 0), Hn - 1), cx0 = min(max(x0, 0), Wn - 1);
        int cy1 = min(max(y1, 0), Hn - 1), cx1 = min(max(x1, 0), Wn - 1);
        float w00 = (vy0 && vx0) ? (1.f - wy) * (1.f - wx) * m : 0.f;
        float w01 = (vy0 && vx1) ? (1.f - wy) * wx * m : 0.f;
        float w10 = (vy1 && vx0) ? wy * (1.f - wx) * m : 0.f;
        float w11 = (vy1 && vx1) ? wy * wx * m : 0.f;
        int g = ((b * 9 + k) << 12) + p;
        midx[g]          = (cy0 << 6) + cx0;
        midx[NM + g]     = (cy0 << 6) + cx1;
        midx[2 * NM + g] = (cy1 << 6) + cx0;
        midx[3 * NM + g] = (cy1 << 6) + cx1;
        mwt[g]          = w00;
        mwt[NM + g]     = w01;
        mwt[2 * NM + g] = w10;
        mwt[3 * NM + g] = w11;
    }
}

// ---- Kernel 3: fused deformable-conv GEMM ----------------------------------
// Block: 64 pixels (one image row) x 128 f. Loop over c in chunks of CCk.
__global__ __launch_bounds__(256) void dconv(const float* __restrict__ x,
                                             const float* __restrict__ wT,
                                             const int* __restrict__ midx,
                                             const float* __restrict__ mwt,
                                             float* __restrict__ out) {
    __shared__ __align__(16) float wl[CCk * 9 * 128];
    __shared__ __align__(16) float sl[CCk * 576];
    const int t = threadIdx.x;
    const int b = blockIdx.z;
    const int p0 = blockIdx.x << 6;
    const int f0 = blockIdx.y << 7;

    // sampling metadata (independent of c) -> registers
    int si0[3], si1[3], si2[3], si3[3];
    float sw0[3], sw1[3], sw2[3], sw3[3];
#pragma unroll
    for (int j = 0; j < 3; ++j) {
        int s = t + (j << 8);
        if (s < 576) {
            int k = s >> 6, pp = s & 63;
            int g = ((b * 9 + k) << 12) + p0 + pp;
            si0[j] = midx[g];          si1[j] = midx[NM + g];
            si2[j] = midx[2 * NM + g]; si3[j] = midx[3 * NM + g];
            sw0[j] = mwt[g];           sw1[j] = mwt[NM + g];
            sw2[j] = mwt[2 * NM + g];  sw3[j] = mwt[3 * NM + g];
        } else {
            si0[j] = si1[j] = si2[j] = si3[j] = 0;
            sw0[j] = sw1[j] = sw2[j] = sw3[j] = 0.f;
        }
    }

    float acc[8][4];
#pragma unroll
    for (int j = 0; j < 8; ++j)
#pragma unroll
        for (int i = 0; i < 4; ++i) acc[j][i] = 0.f;

    const int pcol = t & 15, frow = t >> 4;

#pragma unroll 1
    for (int c0 = 0; c0 < Cn; c0 += CCk) {
        __syncthreads();
        // stage weights: CCk*9*128 floats, coalesced from wT
#pragma unroll
        for (int it = 0; it < (CCk * 9 * 128) / 256; ++it) {
            int i = t + (it << 8);
            wl[i] = wT[((c0 * 9 + (i >> 7)) << 8) + f0 + (i & 127)];
        }
        // stage samples: bilinear gather per (cc, k, p)
#pragma unroll
        for (int cc = 0; cc < CCk; ++cc) {
            const float* xb = x + (((b << 8) + c0 + cc) << 12);
#pragma unroll
            for (int j = 0; j < 3; ++j) {
                int s = t + (j << 8);
                if (s < 576) {
                    float v = sw0[j] * xb[si0[j]];
                    v = fmaf(sw1[j], xb[si1[j]], v);
                    v = fmaf(sw2[j], xb[si2[j]], v);
                    v = fmaf(sw3[j], xb[si3[j]], v);
                    sl[cc * 576 + s] = v;
                }
            }
        }
        __syncthreads();
        // compute: 8f x 4p register tile per thread
#pragma unroll
        for (int cc = 0; cc < CCk; ++cc) {
#pragma unroll
            for (int k = 0; k < 9; ++k) {
                const float4 s4 = *(const float4*)&sl[cc * 576 + (k << 6) + (pcol << 2)];
                const float4 wa = *(const float4*)&wl[(cc * 9 + k) * 128 + (frow << 3)];
                const float4 wb = *(const float4*)&wl[(cc * 9 + k) * 128 + (frow << 3) + 4];
                float sf[4] = {s4.x, s4.y, s4.z, s4.w};
                float wf[8] = {wa.x, wa.y, wa.z, wa.w, wb.x, wb.y, wb.z, wb.w};
#pragma unroll
                for (int j = 0; j < 8; ++j)
#pragma unroll
                    for (int i = 0; i < 4; ++i)
                        acc[j][i] = fmaf(wf[j], sf[i], acc[j][i]);
            }
        }
    }

#pragma unroll
    for (int j = 0; j < 8; ++j) {
        float4 o = make_float4(acc[j][0], acc[j][1], acc[j][2], acc[j][3]);
        int f = f0 + (frow << 3) + j;
        *(float4*)&out[(((b << 8) + f) << 12) + p0 + (pcol << 2)] = o;
    }
}

extern "C" void kernel_launch(void* const* d_in, const int* in_sizes, int n_in,
                              void* d_out, int out_size, void* d_ws, size_t ws_size,
                              hipStream_t stream) {
    const float* x  = (const float*)d_in[0];
    const float* wo = (const float*)d_in[1];
    const float* wm = (const float*)d_in[2];
    const float* wd = (const float*)d_in[3];
    float* out = (float*)d_out;

    // workspace layout (floats): [4*NM int midx][4*NM float mwt][wT 589824]
    int*   midx = (int*)d_ws;
    float* mwt  = (float*)d_ws + 4 * (size_t)NM;
    float* wT   = (float*)d_ws + 8 * (size_t)NM;

    wtrans<<<dim3((Fn * Cn * Kn + 255) / 256), dim3(256), 0, stream>>>(wd, wT);
    offmask<<<dim3(4, 8, 8), dim3(16, 8), 0, stream>>>(x, wo, wm, midx, mwt);
    dconv<<<dim3(64, 2, 8), dim3(256), 0, stream>>>(x, wT, midx, mwt, out);
}

// Round 3
// 1156.596 us; speedup vs baseline: 2.0553x; 2.0553x over previous
//
#include <hip/hip_runtime.h>
#include <math.h>

constexpr int Bn = 8, Cn = 256, Hn = 64, Wn = 64, Fn = 256, Kn = 9;
constexpr int HWn = Hn * Wn;               // 4096
constexpr int NM = Bn * Kn * HWn;          // 294912 meta elements per array
constexpr int CCk = 4;                     // c-channels per K-chunk in dconv
constexpr int NCH = 4, CCH = 64;           // offconv: 4 chunks x 64 channels

// ---------------- Kernel 1: weight transpose w[f][c*9+k] -> wT[c*9+k][f] ----
__global__ __launch_bounds__(256) void wtrans(const float* __restrict__ wd,
                                              float* __restrict__ wT) {
    int i = blockIdx.x * 256 + threadIdx.x;
    if (i < Fn * Cn * Kn) {
        int f = i / (Cn * Kn);
        int ck = i - f * (Cn * Kn);
        wT[ck * Fn + f] = wd[i];
    }
}

// ---- Kernel 2a: offset/mask 3x3 conv, split over C into NCH partials -------
// part[((ch*8 + b)*27 + oc)*4096 + p]
__global__ __launch_bounds__(256) void offconv(const float* __restrict__ x,
                                               const float* __restrict__ wo,
                                               const float* __restrict__ wm,
                                               float* __restrict__ part) {
    __shared__ float xs[8][18][20];
    __shared__ __align__(16) float wl[8][27][12];
    const int t = threadIdx.x;
    const int tile = blockIdx.x, ch = blockIdx.y, b = blockIdx.z;
    const int h0 = (tile >> 2) << 4, w0 = (tile & 3) << 4;
    const int ty = t >> 4, tx = t & 15;

    float acc[27];
#pragma unroll
    for (int i = 0; i < 27; ++i) acc[i] = 0.f;

#pragma unroll 1
    for (int c0 = ch * CCH; c0 < ch * CCH + CCH; c0 += 8) {
        __syncthreads();
        // stage x: 8 x 18 x 18 halo tile
        for (int i = t; i < 8 * 324; i += 256) {
            int cc = i / 324;
            int r = i - cc * 324;
            int ry = r / 18, rx = r - (r / 18) * 18;
            int gy = h0 - 1 + ry, gx = w0 - 1 + rx;
            float v = 0.f;
            if (gy >= 0 && gy < Hn && gx >= 0 && gx < Wn)
                v = x[(((b * Cn + c0 + cc) * Hn + gy) << 6) + gx];
            xs[cc][ry][rx] = v;
        }
        // stage weights: 8 x 27 x 9
        for (int i = t; i < 8 * 243; i += 256) {
            int cc = i / 243;
            int r = i - cc * 243;
            int oc = r / 9, k = r - (r / 9) * 9;
            float v = (oc < 18) ? wo[(oc * Cn + c0 + cc) * 9 + k]
                                : wm[((oc - 18) * Cn + c0 + cc) * 9 + k];
            wl[cc][oc][k] = v;
        }
        __syncthreads();
#pragma unroll
        for (int cc = 0; cc < 8; ++cc) {
            float xv[9];
#pragma unroll
            for (int ky = 0; ky < 3; ++ky)
#pragma unroll
                for (int kx = 0; kx < 3; ++kx)
                    xv[ky * 3 + kx] = xs[cc][ty + ky][tx + kx];
#pragma unroll
            for (int oc = 0; oc < 27; ++oc) {
                const float4 wa = *(const float4*)&wl[cc][oc][0];
                const float4 wb = *(const float4*)&wl[cc][oc][4];
                const float w8 = wl[cc][oc][8];
                float a = acc[oc];
                a = fmaf(xv[0], wa.x, a);
                a = fmaf(xv[1], wa.y, a);
                a = fmaf(xv[2], wa.z, a);
                a = fmaf(xv[3], wa.w, a);
                a = fmaf(xv[4], wb.x, a);
                a = fmaf(xv[5], wb.y, a);
                a = fmaf(xv[6], wb.z, a);
                a = fmaf(xv[7], wb.w, a);
                a = fmaf(xv[8], w8, a);
                acc[oc] = a;
            }
        }
    }

    const int p = ((h0 + ty) << 6) + w0 + tx;
#pragma unroll
    for (int oc = 0; oc < 27; ++oc)
        part[(((ch * Bn + b) * 27 + oc) << 12) + p] = acc[oc];
}

// ---- Kernel 2b: reduce partials + sampling metadata ------------------------
__global__ __launch_bounds__(256) void metafin(const float* __restrict__ part,
                                               int* __restrict__ midx,
                                               float* __restrict__ mwt) {
    const int idx = blockIdx.x * 256 + threadIdx.x;   // over Bn*HWn
    const int b = idx >> 12, p = idx & 4095;
    const int h = p >> 6, w = p & 63;

    float acc[27];
#pragma unroll
    for (int i = 0; i < 27; ++i) acc[i] = 0.f;
#pragma unroll
    for (int ch = 0; ch < NCH; ++ch)
#pragma unroll
        for (int oc = 0; oc < 27; ++oc)
            acc[oc] += part[(((ch * Bn + b) * 27 + oc) << 12) + p];

#pragma unroll
    for (int k = 0; k < 9; ++k) {
        float dy = acc[2 * k], dx = acc[2 * k + 1];
        float m = 1.f / (1.f + expf(-acc[18 + k]));
        float yy = (float)(h + k / 3 - 1) + dy;
        float xx = (float)(w + k % 3 - 1) + dx;
        float y0f = floorf(yy), x0f = floorf(xx);
        float wy = yy - y0f, wx = xx - x0f;
        int y0 = (int)y0f, x0 = (int)x0f;
        int y1 = y0 + 1, x1 = x0 + 1;
        bool vy0 = (unsigned)y0 < (unsigned)Hn;
        bool vx0 = (unsigned)x0 < (unsigned)Wn;
        bool vy1 = (unsigned)y1 < (unsigned)Hn;
        bool vx1 = (unsigned)x1 < (unsigned)Wn;
        int cy0 = min(max(y0, 0), Hn - 1), cx0 = min(max(x0, 0), Wn - 1);
        int cy1 = min(max(y1, 0), Hn - 1), cx1 = min(max(x1, 0), Wn - 1);
        float w00 = (vy0 && vx0) ? (1.f - wy) * (1.f - wx) * m : 0.f;
        float w01 = (vy0 && vx1) ? (1.f - wy) * wx * m : 0.f;
        float w10 = (vy1 && vx0) ? wy * (1.f - wx) * m : 0.f;
        float w11 = (vy1 && vx1) ? wy * wx * m : 0.f;
        int g = ((b * 9 + k) << 12) + p;
        midx[g]          = (cy0 << 6) + cx0;
        midx[NM + g]     = (cy0 << 6) + cx1;
        midx[2 * NM + g] = (cy1 << 6) + cx0;
        midx[3 * NM + g] = (cy1 << 6) + cx1;
        mwt[g]          = w00;
        mwt[NM + g]     = w01;
        mwt[2 * NM + g] = w10;
        mwt[3 * NM + g] = w11;
    }
}

// ---- Kernel 3: fused deformable-conv GEMM ----------------------------------
// Block: 64 pixels (one image row) x 128 f. Loop over c in chunks of CCk.
__global__ __launch_bounds__(256) void dconv(const float* __restrict__ x,
                                             const float* __restrict__ wT,
                                             const int* __restrict__ midx,
                                             const float* __restrict__ mwt,
                                             float* __restrict__ out) {
    __shared__ __align__(16) float wl[CCk * 9 * 128];
    __shared__ __align__(16) float sl[CCk * 576];
    const int t = threadIdx.x;
    const int b = blockIdx.z;
    const int p0 = blockIdx.x << 6;
    const int f0 = blockIdx.y << 7;

    // sampling metadata (independent of c) -> registers
    int si0[3], si1[3], si2[3], si3[3];
    float sw0[3], sw1[3], sw2[3], sw3[3];
#pragma unroll
    for (int j = 0; j < 3; ++j) {
        int s = t + (j << 8);
        if (s < 576) {
            int k = s >> 6, pp = s & 63;
            int g = ((b * 9 + k) << 12) + p0 + pp;
            si0[j] = midx[g];          si1[j] = midx[NM + g];
            si2[j] = midx[2 * NM + g]; si3[j] = midx[3 * NM + g];
            sw0[j] = mwt[g];           sw1[j] = mwt[NM + g];
            sw2[j] = mwt[2 * NM + g];  sw3[j] = mwt[3 * NM + g];
        } else {
            si0[j] = si1[j] = si2[j] = si3[j] = 0;
            sw0[j] = sw1[j] = sw2[j] = sw3[j] = 0.f;
        }
    }

    float acc[8][4];
#pragma unroll
    for (int j = 0; j < 8; ++j)
#pragma unroll
        for (int i = 0; i < 4; ++i) acc[j][i] = 0.f;

    const int pcol = t & 15, frow = t >> 4;

#pragma unroll 1
    for (int c0 = 0; c0 < Cn; c0 += CCk) {
        __syncthreads();
        // stage weights: CCk*9*128 floats, coalesced from wT
#pragma unroll
        for (int it = 0; it < (CCk * 9 * 128) / 256; ++it) {
            int i = t + (it << 8);
            wl[i] = wT[((c0 * 9 + (i >> 7)) << 8) + f0 + (i & 127)];
        }
        // stage samples: bilinear gather per (cc, k, p)
#pragma unroll
        for (int cc = 0; cc < CCk; ++cc) {
            const float* xb = x + (((b << 8) + c0 + cc) << 12);
#pragma unroll
            for (int j = 0; j < 3; ++j) {
                int s = t + (j << 8);
                if (s < 576) {
                    float v = sw0[j] * xb[si0[j]];
                    v = fmaf(sw1[j], xb[si1[j]], v);
                    v = fmaf(sw2[j], xb[si2[j]], v);
                    v = fmaf(sw3[j], xb[si3[j]], v);
                    sl[cc * 576 + s] = v;
                }
            }
        }
        __syncthreads();
        // compute: 8f x 4p register tile per thread
#pragma unroll
        for (int cc = 0; cc < CCk; ++cc) {
#pragma unroll
            for (int k = 0; k < 9; ++k) {
                const float4 s4 = *(const float4*)&sl[cc * 576 + (k << 6) + (pcol << 2)];
                const float4 wa = *(const float4*)&wl[(cc * 9 + k) * 128 + (frow << 3)];
                const float4 wb = *(const float4*)&wl[(cc * 9 + k) * 128 + (frow << 3) + 4];
                float sf[4] = {s4.x, s4.y, s4.z, s4.w};
                float wf[8] = {wa.x, wa.y, wa.z, wa.w, wb.x, wb.y, wb.z, wb.w};
#pragma unroll
                for (int j = 0; j < 8; ++j)
#pragma unroll
                    for (int i = 0; i < 4; ++i)
                        acc[j][i] = fmaf(wf[j], sf[i], acc[j][i]);
            }
        }
    }

#pragma unroll
    for (int j = 0; j < 8; ++j) {
        float4 o = make_float4(acc[j][0], acc[j][1], acc[j][2], acc[j][3]);
        int f = f0 + (frow << 3) + j;
        *(float4*)&out[(((b << 8) + f) << 12) + p0 + (pcol << 2)] = o;
    }
}

extern "C" void kernel_launch(void* const* d_in, const int* in_sizes, int n_in,
                              void* d_out, int out_size, void* d_ws, size_t ws_size,
                              hipStream_t stream) {
    const float* x  = (const float*)d_in[0];
    const float* wo = (const float*)d_in[1];
    const float* wm = (const float*)d_in[2];
    const float* wd = (const float*)d_in[3];
    float* out = (float*)d_out;

    // ws layout (floats): [4*NM int midx][4*NM float mwt][part (overlaid wT)]
    // part (NCH*Bn*27*4096 = 3538944 floats) is dead after metafin; wtrans
    // then writes wT (589824 floats) into the same region before dconv.
    int*   midx = (int*)d_ws;
    float* mwt  = (float*)d_ws + 4 * (size_t)NM;
    float* part = (float*)d_ws + 8 * (size_t)NM;
    float* wT   = part;

    offconv<<<dim3(16, NCH, Bn), dim3(256), 0, stream>>>(x, wo, wm, part);
    metafin<<<dim3(Bn * HWn / 256), dim3(256), 0, stream>>>(part, midx, mwt);
    wtrans<<<dim3((Fn * Cn * Kn + 255) / 256), dim3(256), 0, stream>>>(wd, wT);
    dconv<<<dim3(64, 2, Bn), dim3(256), 0, stream>>>(x, wT, midx, mwt, out);
}

// Round 6
// 593.097 us; speedup vs baseline: 4.0081x; 1.9501x over previous
//
#include <hip/hip_runtime.h>
#include <hip/hip_bf16.h>
#include <math.h>

constexpr int Bn = 8, Cn = 256, Hn = 64, Wn = 64, Fn = 256, Kn = 9;
constexpr int HWn = Hn * Wn;               // 4096
constexpr int NM = Bn * Kn * HWn;          // 294912 meta entries (int4/float4 each)
constexpr int NCH = 4, CCH = 64;           // offconv split; dconv c-chunk = 64

using frag_ab = __attribute__((ext_vector_type(8))) short;   // 8 bf16 = 4 VGPR
using f32x4   = __attribute__((ext_vector_type(4))) float;

// ---- Kernel 1: pack weights to bf16, MFMA A-frag-linear layout -------------
// wB flat index (((k*16 + ft)*32 + G)*16 + fi)*8 + ci  <-  wd[(f*Cn+c)*9+k],
// f = 16*ft+fi, c = 8*G+ci. Per-MFMA frag load = 64 lanes x 16B contiguous.
__global__ __launch_bounds__(256) void wtrans2(const float* __restrict__ wd,
                                               ushort* __restrict__ wB) {
    int i = blockIdx.x * 256 + threadIdx.x;
    if (i >= Fn * Cn * Kn) return;
    int ci = i & 7, fi = (i >> 3) & 15, G = (i >> 7) & 31, ft = (i >> 12) & 15, k = i >> 16;
    int f = ft * 16 + fi, c = G * 8 + ci;
    union { float f; uint32_t u; } un{wd[(f * Cn + c) * 9 + k]};
    uint32_t r = (un.u + 0x7FFF + ((un.u >> 16) & 1)) >> 16;   // RNE to bf16
    wB[i] = (ushort)r;
}

// ---- Kernel 2a: offset/mask 3x3 conv, split over C into NCH partials -------
__global__ __launch_bounds__(256) void offconv(const float* __restrict__ x,
                                               const float* __restrict__ wo,
                                               const float* __restrict__ wm,
                                               float* __restrict__ part) {
    __shared__ float xs[8][18][20];
    __shared__ __align__(16) float wl[8][27][12];
    const int t = threadIdx.x;
    const int tile = blockIdx.x, ch = blockIdx.y, b = blockIdx.z;
    const int h0 = (tile >> 2) << 4, w0 = (tile & 3) << 4;
    const int ty = t >> 4, tx = t & 15;

    float acc[27];
#pragma unroll
    for (int i = 0; i < 27; ++i) acc[i] = 0.f;

#pragma unroll 1
    for (int c0 = ch * CCH; c0 < ch * CCH + CCH; c0 += 8) {
        __syncthreads();
        for (int i = t; i < 8 * 324; i += 256) {
            int cc = i / 324;
            int r = i - cc * 324;
            int ry = r / 18, rx = r - (r / 18) * 18;
            int gy = h0 - 1 + ry, gx = w0 - 1 + rx;
            float v = 0.f;
            if (gy >= 0 && gy < Hn && gx >= 0 && gx < Wn)
                v = x[(((b * Cn + c0 + cc) * Hn + gy) << 6) + gx];
            xs[cc][ry][rx] = v;
        }
        for (int i = t; i < 8 * 243; i += 256) {
            int cc = i / 243;
            int r = i - cc * 243;
            int oc = r / 9, k = r - (r / 9) * 9;
            float v = (oc < 18) ? wo[(oc * Cn + c0 + cc) * 9 + k]
                                : wm[((oc - 18) * Cn + c0 + cc) * 9 + k];
            wl[cc][oc][k] = v;
        }
        __syncthreads();
#pragma unroll
        for (int cc = 0; cc < 8; ++cc) {
            float xv[9];
#pragma unroll
            for (int ky = 0; ky < 3; ++ky)
#pragma unroll
                for (int kx = 0; kx < 3; ++kx)
                    xv[ky * 3 + kx] = xs[cc][ty + ky][tx + kx];
#pragma unroll
            for (int oc = 0; oc < 27; ++oc) {
                const float4 wa = *(const float4*)&wl[cc][oc][0];
                const float4 wb = *(const float4*)&wl[cc][oc][4];
                const float w8 = wl[cc][oc][8];
                float a = acc[oc];
                a = fmaf(xv[0], wa.x, a);
                a = fmaf(xv[1], wa.y, a);
                a = fmaf(xv[2], wa.z, a);
                a = fmaf(xv[3], wa.w, a);
                a = fmaf(xv[4], wb.x, a);
                a = fmaf(xv[5], wb.y, a);
                a = fmaf(xv[6], wb.z, a);
                a = fmaf(xv[7], wb.w, a);
                a = fmaf(xv[8], w8, a);
                acc[oc] = a;
            }
        }
    }

    const int p = ((h0 + ty) << 6) + w0 + tx;
#pragma unroll
    for (int oc = 0; oc < 27; ++oc)
        part[(((ch * Bn + b) * 27 + oc) << 12) + p] = acc[oc];
}

// ---- Kernel 2b: reduce partials + packed sampling metadata -----------------
__global__ __launch_bounds__(256) void metafin(const float* __restrict__ part,
                                               int4* __restrict__ midx4,
                                               float4* __restrict__ mwt4) {
    const int idx = blockIdx.x * 256 + threadIdx.x;   // over Bn*HWn
    const int b = idx >> 12, p = idx & 4095;
    const int h = p >> 6, w = p & 63;

    float acc[27];
#pragma unroll
    for (int i = 0; i < 27; ++i) acc[i] = 0.f;
#pragma unroll
    for (int ch = 0; ch < NCH; ++ch)
#pragma unroll
        for (int oc = 0; oc < 27; ++oc)
            acc[oc] += part[(((ch * Bn + b) * 27 + oc) << 12) + p];

#pragma unroll
    for (int k = 0; k < 9; ++k) {
        float dy = acc[2 * k], dx = acc[2 * k + 1];
        float m = 1.f / (1.f + expf(-acc[18 + k]));
        float yy = (float)(h + k / 3 - 1) + dy;
        float xx = (float)(w + k % 3 - 1) + dx;
        float y0f = floorf(yy), x0f = floorf(xx);
        float wy = yy - y0f, wx = xx - x0f;
        int y0 = (int)y0f, x0 = (int)x0f;
        int y1 = y0 + 1, x1 = x0 + 1;
        bool vy0 = (unsigned)y0 < (unsigned)Hn;
        bool vx0 = (unsigned)x0 < (unsigned)Wn;
        bool vy1 = (unsigned)y1 < (unsigned)Hn;
        bool vx1 = (unsigned)x1 < (unsigned)Wn;
        int cy0 = min(max(y0, 0), Hn - 1), cx0 = min(max(x0, 0), Wn - 1);
        int cy1 = min(max(y1, 0), Hn - 1), cx1 = min(max(x1, 0), Wn - 1);
        float w00 = (vy0 && vx0) ? (1.f - wy) * (1.f - wx) * m : 0.f;
        float w01 = (vy0 && vx1) ? (1.f - wy) * wx * m : 0.f;
        float w10 = (vy1 && vx0) ? wy * (1.f - wx) * m : 0.f;
        float w11 = (vy1 && vx1) ? wy * wx * m : 0.f;
        int q = ((b * 9 + k) << 12) + p;
        midx4[q] = make_int4((cy0 << 6) + cx0, (cy0 << 6) + cx1,
                             (cy1 << 6) + cx0, (cy1 << 6) + cx1);
        mwt4[q] = make_float4(w00, w01, w10, w11);
    }
}

// ---- Kernel 3: bf16 MFMA deformable-conv GEMM ------------------------------
// Block: 512 thr (8 waves), tile F=256 x P=64 (one image row). Wave w owns
// f=32w..32w+31. Steps: (k 0..8) x (ch 0..3 of 64 c). LDS sl[p][64c] bf16,
// 128B rows, XOR-swizzled 16B slots, double-buffered.
__global__ __launch_bounds__(512, 4) void dconv(const float* __restrict__ x,
                                                const ushort* __restrict__ wB,
                                                const int4* __restrict__ midx4,
                                                const float4* __restrict__ mwt4,
                                                float* __restrict__ out) {
    __shared__ ushort sl[2][64][64];
    const int t = threadIdx.x;
    const int l = t & 63, w = t >> 6;
    const int li = l & 15, lg = l >> 4;
    const int b = blockIdx.y;
    const int p0 = blockIdx.x << 6;

    f32x4 acc[2][4];
#pragma unroll
    for (int a = 0; a < 2; ++a)
#pragma unroll
        for (int q = 0; q < 4; ++q) acc[a][q] = (f32x4)0.f;

    int4 mi;           // meta for staging (p = l fixed per thread)
    float4 mw;
    const float* xb_b = x + (size_t)b * Cn * HWn;

    auto STAGE = [&](int s, int buf) {
        const int k = s >> 2, ch = s & 3;
        if ((s & 3) == 0) {
            int q = ((b * 9 + k) << 12) + p0 + l;
            mi = midx4[q];
            mw = mwt4[q];
        }
        const float* xc = xb_b + (size_t)(ch * CCH + w * 8) * HWn;
        uint32_t pk[4];
#pragma unroll
        for (int jq = 0; jq < 4; ++jq) {
            float sv[2];
#pragma unroll
            for (int e = 0; e < 2; ++e) {
                const float* xj = xc + (2 * jq + e) * HWn;
                float v = mw.x * xj[mi.x];
                v = fmaf(mw.y, xj[mi.y], v);
                v = fmaf(mw.z, xj[mi.z], v);
                v = fmaf(mw.w, xj[mi.w], v);
                sv[e] = v;
            }
            __hip_bfloat162 h2 = __float22bfloat162_rn(make_float2(sv[0], sv[1]));
            pk[jq] = *reinterpret_cast<uint32_t*>(&h2);
        }
        const int slot = (w ^ (l & 7)) << 3;
        *(int4*)&sl[buf][l][slot] =
            make_int4((int)pk[0], (int)pk[1], (int)pk[2], (int)pk[3]);
    };

    auto COMPUTE = [&](int s, int buf) {
        const int k = s >> 2, ch = s & 3;
        const ushort* wp = wB + ((size_t)((k * 16 + 2 * w) * 512 + ch * 128)) * 8;
#pragma unroll
        for (int h = 0; h < 2; ++h) {
            frag_ab bq[4];
#pragma unroll
            for (int pt = 0; pt < 4; ++pt)
                bq[pt] = *(const frag_ab*)&sl[buf][pt * 16 + li]
                                            [((((h << 2) | lg) ^ (l & 7)) << 3)];
#pragma unroll
            for (int ft = 0; ft < 2; ++ft) {
                frag_ab a = *(const frag_ab*)(wp + (size_t)(ft * 512 + h * 64 + l) * 8);
#pragma unroll
                for (int pt = 0; pt < 4; ++pt)
                    acc[ft][pt] = __builtin_amdgcn_mfma_f32_16x16x32_bf16(
                        a, bq[pt], acc[ft][pt], 0, 0, 0);
            }
        }
    };

    STAGE(0, 0);
    __syncthreads();
#pragma unroll 1
    for (int s = 0; s < 36; ++s) {
        const int cur = s & 1;
        if (s + 1 < 36) STAGE(s + 1, cur ^ 1);
        COMPUTE(s, cur);
        __syncthreads();
    }

    float* ob = out + (size_t)b * Fn * HWn + p0;
#pragma unroll
    for (int ft = 0; ft < 2; ++ft)
#pragma unroll
        for (int j = 0; j < 4; ++j) {
            int f = w * 32 + ft * 16 + lg * 4 + j;
#pragma unroll
            for (int pt = 0; pt < 4; ++pt)
                ob[(size_t)f * HWn + pt * 16 + li] = acc[ft][pt][j];
        }
}

extern "C" void kernel_launch(void* const* d_in, const int* in_sizes, int n_in,
                              void* d_out, int out_size, void* d_ws, size_t ws_size,
                              hipStream_t stream) {
    const float* x  = (const float*)d_in[0];
    const float* wo = (const float*)d_in[1];
    const float* wm = (const float*)d_in[2];
    const float* wd = (const float*)d_in[3];
    float* out = (float*)d_out;

    // ws: [midx4 int4[NM] 4.7MB][mwt4 float4[NM] 4.7MB][part 14.2MB (wB bf16
    // overlays part after metafin consumes it)]
    int4*   midx4 = (int4*)d_ws;
    float4* mwt4  = (float4*)((char*)d_ws + (size_t)NM * 16);
    float*  part  = (float*)((char*)d_ws + (size_t)NM * 32);
    ushort* wBp   = (ushort*)part;

    offconv<<<dim3(16, NCH, Bn), dim3(256), 0, stream>>>(x, wo, wm, part);
    metafin<<<dim3(Bn * HWn / 256), dim3(256), 0, stream>>>(part, midx4, mwt4);
    wtrans2<<<dim3((Fn * Cn * Kn + 255) / 256), dim3(256), 0, stream>>>(wd, wBp);
    dconv<<<dim3(HWn / 64, Bn), dim3(512), 0, stream>>>(x, wBp, midx4, mwt4, out);
}

// Round 8
// 255.513 us; speedup vs baseline: 9.3036x; 2.3212x over previous
//
#include <hip/hip_runtime.h>
#include <hip/hip_bf16.h>
#include <math.h>

constexpr int Bn = 8, Cn = 256, Hn = 64, Wn = 64, Fn = 256, Kn = 9;
constexpr int HWn = Hn * Wn;               // 4096
constexpr int NM = Bn * Kn * HWn;          // 294912 meta entries (int4/float4 each)
constexpr int NCH = 4;                     // c-split for offconv partials

using frag_ab = __attribute__((ext_vector_type(8))) short;   // 8 bf16 = 4 VGPR
using f32x4   = __attribute__((ext_vector_type(4))) float;

__device__ inline ushort f2bf(float f) {
    union { float f; uint32_t u; } un{f};
    return (ushort)((un.u + 0x7FFF + ((un.u >> 16) & 1)) >> 16);   // RNE
}

// ---- Kernel 1: pack deform weights to bf16, MFMA A-frag-linear layout ------
__global__ __launch_bounds__(256) void wtrans2(const float* __restrict__ wd,
                                               ushort* __restrict__ wB) {
    int i = blockIdx.x * 256 + threadIdx.x;
    if (i >= Fn * Cn * Kn) return;
    int ci = i & 7, fi = (i >> 3) & 15, G = (i >> 7) & 31, ft = (i >> 12) & 15, k = i >> 16;
    int f = ft * 16 + fi, c = G * 8 + ci;
    wB[i] = f2bf(wd[(f * Cn + c) * 9 + k]);
}

// ---- Kernel 1b: pack offset/mask weights (27 rows, pad to 32) as A-frags ---
// wA[((tap*8 + cblk)*2 + mt)*512 + l*8 + ci]: m = mt*16+(l&15),
// c = cblk*32 + ((l>>4)&3)*8 + ci. 73728 ushorts = 147 KB.
__global__ __launch_bounds__(256) void wpack27(const float* __restrict__ wo,
                                               const float* __restrict__ wm,
                                               ushort* __restrict__ wA) {
    int i = blockIdx.x * 256 + threadIdx.x;
    if (i >= 73728) return;
    int ci = i & 7, l = (i >> 3) & 63, mt = (i >> 9) & 1, cblk = (i >> 10) & 7, tap = i >> 13;
    int m = mt * 16 + (l & 15);
    int c = cblk * 32 + ((l >> 4) & 3) * 8 + ci;
    float v = 0.f;
    if (m < 18)      v = wo[(m * Cn + c) * 9 + tap];
    else if (m < 27) v = wm[((m - 18) * Cn + c) * 9 + tap];
    wA[i] = f2bf(v);
}

// ---- Kernel 2a: offset/mask conv via MFMA, split over C into NCH partials --
// Block: 256 thr (4 waves), 2 image rows, 64 c. Wave w: row rw=w>>1,
// pixel-tiles pt0=(w&1)*2..+1. LDS halo tile [4 rows][66 cols][40 c] bf16.
__global__ __launch_bounds__(256) void offconv27(const float* __restrict__ x,
                                                 const ushort* __restrict__ wA,
                                                 float* __restrict__ part) {
    __shared__ ushort xs[4][66][40];
    const int t = threadIdx.x;
    const int l = t & 63, w = t >> 6;
    const int li = l & 15, lg = l >> 4;
    const int rb = blockIdx.x, ch = blockIdx.y, b = blockIdx.z;
    const int h0 = rb * 2;
    const int rw = w >> 1, pt0 = (w & 1) * 2;

    f32x4 acc[2][2];
#pragma unroll
    for (int mt = 0; mt < 2; ++mt)
#pragma unroll
        for (int q = 0; q < 2; ++q) acc[mt][q] = (f32x4)0.f;

    const float* xb = x + (size_t)b * Cn * HWn;

#pragma unroll 1
    for (int cc = 0; cc < 2; ++cc) {
        const int cbase = ch * 64 + cc * 32;
        __syncthreads();
        // stage 32c x 4rows x 66cols halo (zero-padded), c-contiguous bf16
        for (int j = t; j < 1056; j += 256) {
            int cq = j / 264;
            int rem = j - cq * 264;
            int r = rem / 66, col = rem - r * 66;
            int rg = h0 - 1 + r, cg = col - 1;
            ushort u[8];
            if ((unsigned)rg < (unsigned)Hn && (unsigned)cg < (unsigned)Wn) {
                const float* xp = xb + (size_t)(cbase + cq * 8) * HWn + (rg << 6) + cg;
#pragma unroll
                for (int jj = 0; jj < 8; ++jj) u[jj] = f2bf(xp[(size_t)jj * HWn]);
            } else {
#pragma unroll
                for (int jj = 0; jj < 8; ++jj) u[jj] = 0;
            }
            *(int4*)&xs[r][col][cq * 8] =
                make_int4(u[0] | (u[1] << 16), u[2] | (u[3] << 16),
                          u[4] | (u[5] << 16), u[6] | (u[7] << 16));
        }
        __syncthreads();
        const int cblk = ch * 2 + cc;
#pragma unroll
        for (int tap = 0; tap < 9; ++tap) {
            const int ky = tap / 3, kx = tap - 3 * (tap / 3);
            frag_ab a0 = *(const frag_ab*)(wA + (size_t)((tap * 8 + cblk) * 2) * 512 + l * 8);
            frag_ab a1 = *(const frag_ab*)(wA + (size_t)((tap * 8 + cblk) * 2 + 1) * 512 + l * 8);
#pragma unroll
            for (int q = 0; q < 2; ++q) {
                frag_ab bf = *(const frag_ab*)&xs[rw + ky][(pt0 + q) * 16 + li + kx][lg * 8];
                acc[0][q] = __builtin_amdgcn_mfma_f32_16x16x32_bf16(a0, bf, acc[0][q], 0, 0, 0);
                acc[1][q] = __builtin_amdgcn_mfma_f32_16x16x32_bf16(a1, bf, acc[1][q], 0, 0, 0);
            }
        }
    }

    const int h = h0 + rw;
#pragma unroll
    for (int mt = 0; mt < 2; ++mt)
#pragma unroll
        for (int j = 0; j < 4; ++j) {
            int m = mt * 16 + lg * 4 + j;
            if (m < 27) {
#pragma unroll
                for (int q = 0; q < 2; ++q) {
                    int pixel = (pt0 + q) * 16 + li;
                    part[((size_t)((ch * Bn + b) * 27 + m) << 12) + (h << 6) + pixel] =
                        acc[mt][q][j];
                }
            }
        }
}

// ---- Kernel 2b: per-k partial reduce + packed sampling metadata ------------
__global__ __launch_bounds__(256) void metafin9(const float* __restrict__ part,
                                                int4* __restrict__ midx4,
                                                float4* __restrict__ mwt4) {
    const int k = blockIdx.y;
    const int idx = blockIdx.x * 256 + threadIdx.x;   // over Bn*HWn
    const int b = idx >> 12, p = idx & 4095;
    const int h = p >> 6, w = p & 63;

    float dy = 0.f, dx = 0.f, ms = 0.f;
#pragma unroll
    for (int ch = 0; ch < NCH; ++ch) {
        size_t base = ((size_t)((ch * Bn + b) * 27) << 12) + p;
        dy += part[base + ((size_t)(2 * k) << 12)];
        dx += part[base + ((size_t)(2 * k + 1) << 12)];
        ms += part[base + ((size_t)(18 + k) << 12)];
    }
    float m = 1.f / (1.f + expf(-ms));
    float yy = (float)(h + k / 3 - 1) + dy;
    float xx = (float)(w + k % 3 - 1) + dx;
    float y0f = floorf(yy), x0f = floorf(xx);
    float wy = yy - y0f, wx = xx - x0f;
    int y0 = (int)y0f, x0 = (int)x0f;
    int y1 = y0 + 1, x1 = x0 + 1;
    bool vy0 = (unsigned)y0 < (unsigned)Hn;
    bool vx0 = (unsigned)x0 < (unsigned)Wn;
    bool vy1 = (unsigned)y1 < (unsigned)Hn;
    bool vx1 = (unsigned)x1 < (unsigned)Wn;
    int cy0 = min(max(y0, 0), Hn - 1), cx0 = min(max(x0, 0), Wn - 1);
    int cy1 = min(max(y1, 0), Hn - 1), cx1 = min(max(x1, 0), Wn - 1);
    float w00 = (vy0 && vx0) ? (1.f - wy) * (1.f - wx) * m : 0.f;
    float w01 = (vy0 && vx1) ? (1.f - wy) * wx * m : 0.f;
    float w10 = (vy1 && vx0) ? wy * (1.f - wx) * m : 0.f;
    float w11 = (vy1 && vx1) ? wy * wx * m : 0.f;
    int q = ((b * 9 + k) << 12) + p;
    midx4[q] = make_int4((cy0 << 6) + cx0, (cy0 << 6) + cx1,
                         (cy1 << 6) + cx0, (cy1 << 6) + cx1);
    mwt4[q] = make_float4(w00, w01, w10, w11);
}

// ---- Kernel 3: bf16 MFMA deformable-conv GEMM (unchanged, passing) ---------
__global__ __launch_bounds__(512, 4) void dconv(const float* __restrict__ x,
                                                const ushort* __restrict__ wB,
                                                const int4* __restrict__ midx4,
                                                const float4* __restrict__ mwt4,
                                                float* __restrict__ out) {
    __shared__ ushort sl[2][64][64];
    const int t = threadIdx.x;
    const int l = t & 63, w = t >> 6;
    const int li = l & 15, lg = l >> 4;
    const int b = blockIdx.y;
    const int p0 = blockIdx.x << 6;

    f32x4 acc[2][4];
#pragma unroll
    for (int a = 0; a < 2; ++a)
#pragma unroll
        for (int q = 0; q < 4; ++q) acc[a][q] = (f32x4)0.f;

    int4 mi;
    float4 mw;
    const float* xb_b = x + (size_t)b * Cn * HWn;

    auto STAGE = [&](int s, int buf) {
        const int k = s >> 2, ch = s & 3;
        if ((s & 3) == 0) {
            int q = ((b * 9 + k) << 12) + p0 + l;
            mi = midx4[q];
            mw = mwt4[q];
        }
        const float* xc = xb_b + (size_t)(ch * 64 + w * 8) * HWn;
        uint32_t pk[4];
#pragma unroll
        for (int jq = 0; jq < 4; ++jq) {
            float sv[2];
#pragma unroll
            for (int e = 0; e < 2; ++e) {
                const float* xj = xc + (2 * jq + e) * HWn;
                float v = mw.x * xj[mi.x];
                v = fmaf(mw.y, xj[mi.y], v);
                v = fmaf(mw.z, xj[mi.z], v);
                v = fmaf(mw.w, xj[mi.w], v);
                sv[e] = v;
            }
            __hip_bfloat162 h2 = __float22bfloat162_rn(make_float2(sv[0], sv[1]));
            pk[jq] = *reinterpret_cast<uint32_t*>(&h2);
        }
        const int slot = (w ^ (l & 7)) << 3;
        *(int4*)&sl[buf][l][slot] =
            make_int4((int)pk[0], (int)pk[1], (int)pk[2], (int)pk[3]);
    };

    auto COMPUTE = [&](int s, int buf) {
        const int k = s >> 2, ch = s & 3;
        const ushort* wp = wB + ((size_t)((k * 16 + 2 * w) * 512 + ch * 128)) * 8;
#pragma unroll
        for (int h = 0; h < 2; ++h) {
            frag_ab bq[4];
#pragma unroll
            for (int pt = 0; pt < 4; ++pt)
                bq[pt] = *(const frag_ab*)&sl[buf][pt * 16 + li]
                                            [((((h << 2) | lg) ^ (l & 7)) << 3)];
#pragma unroll
            for (int ft = 0; ft < 2; ++ft) {
                frag_ab a = *(const frag_ab*)(wp + (size_t)(ft * 512 + h * 64 + l) * 8);
#pragma unroll
                for (int pt = 0; pt < 4; ++pt)
                    acc[ft][pt] = __builtin_amdgcn_mfma_f32_16x16x32_bf16(
                        a, bq[pt], acc[ft][pt], 0, 0, 0);
            }
        }
    };

    STAGE(0, 0);
    __syncthreads();
#pragma unroll 1
    for (int s = 0; s < 36; ++s) {
        const int cur = s & 1;
        if (s + 1 < 36) STAGE(s + 1, cur ^ 1);
        COMPUTE(s, cur);
        __syncthreads();
    }

    float* ob = out + (size_t)b * Fn * HWn + p0;
#pragma unroll
    for (int ft = 0; ft < 2; ++ft)
#pragma unroll
        for (int j = 0; j < 4; ++j) {
            int f = w * 32 + ft * 16 + lg * 4 + j;
#pragma unroll
            for (int pt = 0; pt < 4; ++pt)
                ob[(size_t)f * HWn + pt * 16 + li] = acc[ft][pt][j];
        }
}

extern "C" void kernel_launch(void* const* d_in, const int* in_sizes, int n_in,
                              void* d_out, int out_size, void* d_ws, size_t ws_size,
                              hipStream_t stream) {
    const float* x  = (const float*)d_in[0];
    const float* wo = (const float*)d_in[1];
    const float* wm = (const float*)d_in[2];
    const float* wd = (const float*)d_in[3];
    float* out = (float*)d_out;

    // ws: [midx4 4.7MB][mwt4 4.7MB][part 14.2MB (wB overlays after metafin)]
    //     [wA27 147KB]
    int4*   midx4 = (int4*)d_ws;
    float4* mwt4  = (float4*)((char*)d_ws + (size_t)NM * 16);
    float*  part  = (float*)((char*)d_ws + (size_t)NM * 32);
    ushort* wBp   = (ushort*)part;
    ushort* wA27  = (ushort*)((char*)d_ws + (size_t)NM * 32 + (size_t)NCH * Bn * 27 * HWn * 4);

    wpack27<<<dim3(288), dim3(256), 0, stream>>>(wo, wm, wA27);
    offconv27<<<dim3(32, NCH, Bn), dim3(256), 0, stream>>>(x, wA27, part);
    metafin9<<<dim3(Bn * HWn / 256, 9), dim3(256), 0, stream>>>(part, midx4, mwt4);
    wtrans2<<<dim3((Fn * Cn * Kn + 255) / 256), dim3(256), 0, stream>>>(wd, wBp);
    dconv<<<dim3(HWn / 64, Bn), dim3(512), 0, stream>>>(x, wBp, midx4, mwt4, out);
}

// Round 9
// 121.420 us; speedup vs baseline: 19.5781x; 2.1044x over previous
//
#include <hip/hip_runtime.h>
#include <hip/hip_bf16.h>
#include <hip/hip_fp16.h>
#include <math.h>

constexpr int Bn = 8, Cn = 256, Hn = 64, Wn = 64, Fn = 256, Kn = 9;
constexpr int HWn = Hn * Wn;               // 4096
constexpr int NM = Bn * Kn * HWn;          // 294912 meta entries (int4 each)
constexpr int NCH = 4;                     // c-split for offconv partials

using frag_ab = __attribute__((ext_vector_type(8))) short;   // 8 bf16 = 4 VGPR
using f32x4   = __attribute__((ext_vector_type(4))) float;

__device__ inline ushort f2bf(float f) {
    union { float f; uint32_t u; } un{f};
    return (ushort)((un.u + 0x7FFF + ((un.u >> 16) & 1)) >> 16);   // RNE
}

// ---- Kernel 1: pack deform weights to bf16, MFMA A-frag-linear layout ------
__global__ __launch_bounds__(256) void wtrans2(const float* __restrict__ wd,
                                               ushort* __restrict__ wB) {
    int i = blockIdx.x * 256 + threadIdx.x;
    if (i >= Fn * Cn * Kn) return;
    int ci = i & 7, fi = (i >> 3) & 15, G = (i >> 7) & 31, ft = (i >> 12) & 15, k = i >> 16;
    int f = ft * 16 + fi, c = G * 8 + ci;
    wB[i] = f2bf(wd[(f * Cn + c) * 9 + k]);
}

// ---- Kernel 1b: pack offset/mask weights (27 rows, pad to 32) as A-frags ---
__global__ __launch_bounds__(256) void wpack27(const float* __restrict__ wo,
                                               const float* __restrict__ wm,
                                               ushort* __restrict__ wA) {
    int i = blockIdx.x * 256 + threadIdx.x;
    if (i >= 73728) return;
    int ci = i & 7, l = (i >> 3) & 63, mt = (i >> 9) & 1, cblk = (i >> 10) & 7, tap = i >> 13;
    int m = mt * 16 + (l & 15);
    int c = cblk * 32 + ((l >> 4) & 3) * 8 + ci;
    float v = 0.f;
    if (m < 18)      v = wo[(m * Cn + c) * 9 + tap];
    else if (m < 27) v = wm[((m - 18) * Cn + c) * 9 + tap];
    wA[i] = f2bf(v);
}

// ---- Kernel 1c: x NCHW f32 -> xh NHWC bf16-pair packed ---------------------
// xu[(b*4096 + p)*128 + c/2] = bf16x2(x[b][c][p], x[b][c+1][p])
__global__ __launch_bounds__(256) void xpose(const float* __restrict__ x,
                                             uint32_t* __restrict__ xu) {
    int i = blockIdx.x * 256 + threadIdx.x;   // over Bn*4*HWn
    int p = i & 4095, q = (i >> 12) & 3, b = i >> 14;
    const float* xp = x + (size_t)b * Cn * HWn + p;
    uint32_t* op = xu + (((size_t)b * 4096 + p) << 7) + q * 32;
#pragma unroll
    for (int j = 0; j < 32; ++j) {
        int c = q * 64 + 2 * j;
        float lo = xp[(size_t)c * HWn];
        float hi = xp[(size_t)(c + 1) * HWn];
        __hip_bfloat162 h2 = __float22bfloat162_rn(make_float2(lo, hi));
        op[j] = *reinterpret_cast<uint32_t*>(&h2);
    }
}

// ---- Kernel 2a: offset/mask conv via MFMA, split over C into NCH partials --
__global__ __launch_bounds__(256) void offconv27(const float* __restrict__ x,
                                                 const ushort* __restrict__ wA,
                                                 float* __restrict__ part) {
    __shared__ ushort xs[4][66][40];
    const int t = threadIdx.x;
    const int l = t & 63, w = t >> 6;
    const int li = l & 15, lg = l >> 4;
    const int rb = blockIdx.x, ch = blockIdx.y, b = blockIdx.z;
    const int h0 = rb * 2;
    const int rw = w >> 1, pt0 = (w & 1) * 2;

    f32x4 acc[2][2];
#pragma unroll
    for (int mt = 0; mt < 2; ++mt)
#pragma unroll
        for (int q = 0; q < 2; ++q) acc[mt][q] = (f32x4)0.f;

    const float* xb = x + (size_t)b * Cn * HWn;

#pragma unroll 1
    for (int cc = 0; cc < 2; ++cc) {
        const int cbase = ch * 64 + cc * 32;
        __syncthreads();
        for (int j = t; j < 1056; j += 256) {
            int cq = j / 264;
            int rem = j - cq * 264;
            int r = rem / 66, col = rem - r * 66;
            int rg = h0 - 1 + r, cg = col - 1;
            ushort u[8];
            if ((unsigned)rg < (unsigned)Hn && (unsigned)cg < (unsigned)Wn) {
                const float* xp = xb + (size_t)(cbase + cq * 8) * HWn + (rg << 6) + cg;
#pragma unroll
                for (int jj = 0; jj < 8; ++jj) u[jj] = f2bf(xp[(size_t)jj * HWn]);
            } else {
#pragma unroll
                for (int jj = 0; jj < 8; ++jj) u[jj] = 0;
            }
            *(int4*)&xs[r][col][cq * 8] =
                make_int4(u[0] | (u[1] << 16), u[2] | (u[3] << 16),
                          u[4] | (u[5] << 16), u[6] | (u[7] << 16));
        }
        __syncthreads();
        const int cblk = ch * 2 + cc;
#pragma unroll
        for (int tap = 0; tap < 9; ++tap) {
            const int ky = tap / 3, kx = tap - 3 * (tap / 3);
            frag_ab a0 = *(const frag_ab*)(wA + (size_t)((tap * 8 + cblk) * 2) * 512 + l * 8);
            frag_ab a1 = *(const frag_ab*)(wA + (size_t)((tap * 8 + cblk) * 2 + 1) * 512 + l * 8);
#pragma unroll
            for (int q = 0; q < 2; ++q) {
                frag_ab bf = *(const frag_ab*)&xs[rw + ky][(pt0 + q) * 16 + li + kx][lg * 8];
                acc[0][q] = __builtin_amdgcn_mfma_f32_16x16x32_bf16(a0, bf, acc[0][q], 0, 0, 0);
                acc[1][q] = __builtin_amdgcn_mfma_f32_16x16x32_bf16(a1, bf, acc[1][q], 0, 0, 0);
            }
        }
    }

    const int h = h0 + rw;
#pragma unroll
    for (int mt = 0; mt < 2; ++mt)
#pragma unroll
        for (int j = 0; j < 4; ++j) {
            int m = mt * 16 + lg * 4 + j;
            if (m < 27) {
#pragma unroll
                for (int q = 0; q < 2; ++q) {
                    int pixel = (pt0 + q) * 16 + li;
                    part[((size_t)((ch * Bn + b) * 27 + m) << 12) + (h << 6) + pixel] =
                        acc[mt][q][j];
                }
            }
        }
}

// ---- Kernel 2b: per-k partial reduce + packed sampling metadata ------------
// mpack[q] = {i00|i01<<16, i10|i11<<16, half2(w00,w01), half2(w10,w11)}
__global__ __launch_bounds__(256) void metafin9(const float* __restrict__ part,
                                                int4* __restrict__ mpack) {
    const int k = blockIdx.y;
    const int idx = blockIdx.x * 256 + threadIdx.x;   // over Bn*HWn
    const int b = idx >> 12, p = idx & 4095;
    const int h = p >> 6, w = p & 63;

    float dy = 0.f, dx = 0.f, ms = 0.f;
#pragma unroll
    for (int ch = 0; ch < NCH; ++ch) {
        size_t base = ((size_t)((ch * Bn + b) * 27) << 12) + p;
        dy += part[base + ((size_t)(2 * k) << 12)];
        dx += part[base + ((size_t)(2 * k + 1) << 12)];
        ms += part[base + ((size_t)(18 + k) << 12)];
    }
    float m = 1.f / (1.f + expf(-ms));
    float yy = (float)(h + k / 3 - 1) + dy;
    float xx = (float)(w + k % 3 - 1) + dx;
    float y0f = floorf(yy), x0f = floorf(xx);
    float wy = yy - y0f, wx = xx - x0f;
    int y0 = (int)y0f, x0 = (int)x0f;
    int y1 = y0 + 1, x1 = x0 + 1;
    bool vy0 = (unsigned)y0 < (unsigned)Hn;
    bool vx0 = (unsigned)x0 < (unsigned)Wn;
    bool vy1 = (unsigned)y1 < (unsigned)Hn;
    bool vx1 = (unsigned)x1 < (unsigned)Wn;
    int cy0 = min(max(y0, 0), Hn - 1), cx0 = min(max(x0, 0), Wn - 1);
    int cy1 = min(max(y1, 0), Hn - 1), cx1 = min(max(x1, 0), Wn - 1);
    float w00 = (vy0 && vx0) ? (1.f - wy) * (1.f - wx) * m : 0.f;
    float w01 = (vy0 && vx1) ? (1.f - wy) * wx * m : 0.f;
    float w10 = (vy1 && vx0) ? wy * (1.f - wx) * m : 0.f;
    float w11 = (vy1 && vx1) ? wy * wx * m : 0.f;
    int i00 = (cy0 << 6) + cx0, i01 = (cy0 << 6) + cx1;
    int i10 = (cy1 << 6) + cx0, i11 = (cy1 << 6) + cx1;
    union { struct { __half a, bh; } h; int i; } pz, pw;
    pz.h.a = __float2half_rn(w00); pz.h.bh = __float2half_rn(w01);
    pw.h.a = __float2half_rn(w10); pw.h.bh = __float2half_rn(w11);
    int q = ((b * 9 + k) << 12) + p;
    mpack[q] = make_int4(i00 | (i01 << 16), i10 | (i11 << 16), pz.i, pw.i);
}

// ---- Kernel 3: bf16 MFMA deformable-conv GEMM, coalesced NHWC staging ------
// Block 512 thr (8 waves), tile F=256 x P=64. STAGE: wave w = pixels w*8..+7,
// all 64 channels; half-wave = pixel parity, lane&31 = channel dword.
__global__ __launch_bounds__(512, 4) void dconv(const uint32_t* __restrict__ xu,
                                                const ushort* __restrict__ wB,
                                                const int4* __restrict__ mpack,
                                                float* __restrict__ out) {
    __shared__ ushort sl[2][64][64];
    const int t = threadIdx.x;
    const int l = t & 63, w = t >> 6;
    const int li = l & 15, lg = l >> 4;
    const int hl = l >> 5;           // pixel parity within pair
    const int cl = l & 31;           // channel-dword lane
    const int b = blockIdx.y;
    const int p0 = blockIdx.x << 6;

    f32x4 acc[2][4];
#pragma unroll
    for (int a = 0; a < 2; ++a)
#pragma unroll
        for (int q = 0; q < 4; ++q) acc[a][q] = (f32x4)0.f;

    int4 m4[4];
    const uint32_t* xb = xu + (((size_t)b) << 19);   // b*4096*128

    auto LOADMETA = [&](int k) {
#pragma unroll
        for (int u = 0; u < 4; ++u) {
            int pix = w * 8 + 2 * u + hl;
            m4[u] = mpack[((b * 9 + k) << 12) + p0 + pix];
        }
    };

    auto STAGE = [&](int s, int buf) {
        const int ch = s & 3;
        const int co = ch * 32 + cl;
#pragma unroll
        for (int u = 0; u < 4; ++u) {
            int i00 = m4[u].x & 0xFFFF, i01 = ((unsigned)m4[u].x) >> 16;
            int i10 = m4[u].y & 0xFFFF, i11 = ((unsigned)m4[u].y) >> 16;
            union { int i; __half2 h; } uz, uw;
            uz.i = m4[u].z; uw.i = m4[u].w;
            float2 flo = __half22float2(uz.h);   // w00, w01
            float2 fhi = __half22float2(uw.h);   // w10, w11
            uint32_t v00 = xb[i00 * 128 + co];
            uint32_t v01 = xb[i01 * 128 + co];
            uint32_t v10 = xb[i10 * 128 + co];
            uint32_t v11 = xb[i11 * 128 + co];
            union { uint32_t u; float f; } c00{v00 << 16}, c01{v01 << 16},
                                           c10{v10 << 16}, c11{v11 << 16};
            union { uint32_t u; float f; } d00{v00 & 0xFFFF0000u}, d01{v01 & 0xFFFF0000u},
                                           d10{v10 & 0xFFFF0000u}, d11{v11 & 0xFFFF0000u};
            float s0 = flo.x * c00.f;
            s0 = fmaf(flo.y, c01.f, s0);
            s0 = fmaf(fhi.x, c10.f, s0);
            s0 = fmaf(fhi.y, c11.f, s0);
            float s1 = flo.x * d00.f;
            s1 = fmaf(flo.y, d01.f, s1);
            s1 = fmaf(fhi.x, d10.f, s1);
            s1 = fmaf(fhi.y, d11.f, s1);
            __hip_bfloat162 h2 = __float22bfloat162_rn(make_float2(s0, s1));
            int pix = w * 8 + 2 * u + hl;
            int slot = (cl >> 2) ^ (pix & 7);
            *(uint32_t*)&sl[buf][pix][(slot << 3) + ((cl & 3) << 1)] =
                *reinterpret_cast<uint32_t*>(&h2);
        }
    };

    auto COMPUTE = [&](int s, int buf) {
        const int k = s >> 2, ch = s & 3;
        const ushort* wp = wB + ((size_t)((k * 16 + 2 * w) * 512 + ch * 128)) * 8;
#pragma unroll
        for (int h = 0; h < 2; ++h) {
            frag_ab bq[4];
#pragma unroll
            for (int pt = 0; pt < 4; ++pt)
                bq[pt] = *(const frag_ab*)&sl[buf][pt * 16 + li]
                                            [((((h << 2) | lg) ^ (l & 7)) << 3)];
#pragma unroll
            for (int ft = 0; ft < 2; ++ft) {
                frag_ab a = *(const frag_ab*)(wp + (size_t)(ft * 512 + h * 64 + l) * 8);
#pragma unroll
                for (int pt = 0; pt < 4; ++pt)
                    acc[ft][pt] = __builtin_amdgcn_mfma_f32_16x16x32_bf16(
                        a, bq[pt], acc[ft][pt], 0, 0, 0);
            }
        }
    };

    LOADMETA(0);
    STAGE(0, 0);
    __syncthreads();
#pragma unroll 1
    for (int s = 0; s < 36; ++s) {
        const int cur = s & 1;
        if (s + 1 < 36) {
            if (((s + 1) & 3) == 0) LOADMETA((s + 1) >> 2);
            STAGE(s + 1, cur ^ 1);
        }
        COMPUTE(s, cur);
        __syncthreads();
    }

    float* ob = out + (size_t)b * Fn * HWn + p0;
#pragma unroll
    for (int ft = 0; ft < 2; ++ft)
#pragma unroll
        for (int j = 0; j < 4; ++j) {
            int f = w * 32 + ft * 16 + lg * 4 + j;
#pragma unroll
            for (int pt = 0; pt < 4; ++pt)
                ob[(size_t)f * HWn + pt * 16 + li] = acc[ft][pt][j];
        }
}

extern "C" void kernel_launch(void* const* d_in, const int* in_sizes, int n_in,
                              void* d_out, int out_size, void* d_ws, size_t ws_size,
                              hipStream_t stream) {
    const float* x  = (const float*)d_in[0];
    const float* wo = (const float*)d_in[1];
    const float* wm = (const float*)d_in[2];
    const float* wd = (const float*)d_in[3];
    float* out = (float*)d_out;

    // ws: [mpack 4.72MB][region 18MB: part(14.16MB, dead after metafin9) then
    //      wB(1.18MB)+xh(16.78MB)][wA27 147KB]  => 23.74MB total (proven size)
    int4*     mpack = (int4*)d_ws;
    char*     region = (char*)d_ws + (size_t)NM * 16;
    float*    part  = (float*)region;
    ushort*   wBp   = (ushort*)region;
    uint32_t* xh    = (uint32_t*)(region + 1179648);
    ushort*   wA27  = (ushort*)(region + 18874368);

    wpack27<<<dim3(288), dim3(256), 0, stream>>>(wo, wm, wA27);
    offconv27<<<dim3(32, NCH, Bn), dim3(256), 0, stream>>>(x, wA27, part);
    metafin9<<<dim3(Bn * HWn / 256, 9), dim3(256), 0, stream>>>(part, mpack);
    wtrans2<<<dim3((Fn * Cn * Kn + 255) / 256), dim3(256), 0, stream>>>(wd, wBp);
    xpose<<<dim3(Bn * 4 * HWn / 256), dim3(256), 0, stream>>>(x, xh);
    dconv<<<dim3(HWn / 64, Bn), dim3(512), 0, stream>>>(xh, wBp, mpack, out);
}

// Round 11
// 113.283 us; speedup vs baseline: 20.9845x; 1.0718x over previous
//
#include <hip/hip_runtime.h>
#include <hip/hip_bf16.h>
#include <hip/hip_fp16.h>
#include <math.h>

constexpr int Bn = 8, Cn = 256, Hn = 64, Wn = 64, Fn = 256, Kn = 9;
constexpr int HWn = Hn * Wn;               // 4096
constexpr int NM = Bn * Kn * HWn;          // 294912 meta entries (int4 each)
constexpr int NCH = 4;                     // c-split for offconv partials

using frag_ab = __attribute__((ext_vector_type(8))) short;     // 8 bf16
using frag_h  = __attribute__((ext_vector_type(8))) _Float16;  // 8 fp16
using f32x4   = __attribute__((ext_vector_type(4))) float;

__device__ inline ushort f2bf(float f) {
    union { float f; uint32_t u; } un{f};
    return (ushort)((un.u + 0x7FFF + ((un.u >> 16) & 1)) >> 16);   // RNE
}
__device__ inline ushort f2h(float f) {
    __half h = __float2half_rn(f);
    return *reinterpret_cast<ushort*>(&h);
}

// ---- Kernel 1: pack deform weights to fp16, MFMA A-frag-linear layout ------
__global__ __launch_bounds__(256) void wtrans2(const float* __restrict__ wd,
                                               ushort* __restrict__ wB) {
    int i = blockIdx.x * 256 + threadIdx.x;
    if (i >= Fn * Cn * Kn) return;
    int ci = i & 7, fi = (i >> 3) & 15, G = (i >> 7) & 31, ft = (i >> 12) & 15, k = i >> 16;
    int f = ft * 16 + fi, c = G * 8 + ci;
    wB[i] = f2h(wd[(f * Cn + c) * 9 + k]);
}

// ---- Kernel 1b: pack offset/mask weights (27 rows, pad to 32) as A-frags ---
__global__ __launch_bounds__(256) void wpack27(const float* __restrict__ wo,
                                               const float* __restrict__ wm,
                                               ushort* __restrict__ wA) {
    int i = blockIdx.x * 256 + threadIdx.x;
    if (i >= 73728) return;
    int ci = i & 7, l = (i >> 3) & 63, mt = (i >> 9) & 1, cblk = (i >> 10) & 7, tap = i >> 13;
    int m = mt * 16 + (l & 15);
    int c = cblk * 32 + ((l >> 4) & 3) * 8 + ci;
    float v = 0.f;
    if (m < 18)      v = wo[(m * Cn + c) * 9 + tap];
    else if (m < 27) v = wm[((m - 18) * Cn + c) * 9 + tap];
    wA[i] = f2bf(v);
}

// ---- Kernel 1c: x NCHW f32 -> xh NHWC fp16-pair packed ---------------------
// xh[(b*4096 + p)*128 + c/2] = half2(x[b][c][p], x[b][c+1][p])
__global__ __launch_bounds__(256) void xpose(const float* __restrict__ x,
                                             __half2* __restrict__ xh) {
    int i = blockIdx.x * 256 + threadIdx.x;   // over Bn*4*HWn
    int p = i & 4095, q = (i >> 12) & 3, b = i >> 14;
    const float* xp = x + (size_t)b * Cn * HWn + p;
    __half2* op = xh + (((size_t)b * 4096 + p) << 7) + q * 32;
#pragma unroll
    for (int j = 0; j < 32; ++j) {
        int c = q * 64 + 2 * j;
        op[j] = __float22half2_rn(make_float2(xp[(size_t)c * HWn],
                                              xp[(size_t)(c + 1) * HWn]));
    }
}

// ---- Kernel 2a: offset/mask conv via MFMA (bf16), split over C -------------
__global__ __launch_bounds__(256) void offconv27(const float* __restrict__ x,
                                                 const ushort* __restrict__ wA,
                                                 float* __restrict__ part) {
    __shared__ ushort xs[4][66][40];
    const int t = threadIdx.x;
    const int l = t & 63, w = t >> 6;
    const int li = l & 15, lg = l >> 4;
    const int rb = blockIdx.x, ch = blockIdx.y, b = blockIdx.z;
    const int h0 = rb * 2;
    const int rw = w >> 1, pt0 = (w & 1) * 2;

    f32x4 acc[2][2];
#pragma unroll
    for (int mt = 0; mt < 2; ++mt)
#pragma unroll
        for (int q = 0; q < 2; ++q) acc[mt][q] = (f32x4)0.f;

    const float* xb = x + (size_t)b * Cn * HWn;

#pragma unroll 1
    for (int cc = 0; cc < 2; ++cc) {
        const int cbase = ch * 64 + cc * 32;
        __syncthreads();
        for (int j = t; j < 1056; j += 256) {
            int cq = j / 264;
            int rem = j - cq * 264;
            int r = rem / 66, col = rem - r * 66;
            int rg = h0 - 1 + r, cg = col - 1;
            ushort u[8];
            if ((unsigned)rg < (unsigned)Hn && (unsigned)cg < (unsigned)Wn) {
                const float* xp = xb + (size_t)(cbase + cq * 8) * HWn + (rg << 6) + cg;
#pragma unroll
                for (int jj = 0; jj < 8; ++jj) u[jj] = f2bf(xp[(size_t)jj * HWn]);
            } else {
#pragma unroll
                for (int jj = 0; jj < 8; ++jj) u[jj] = 0;
            }
            *(int4*)&xs[r][col][cq * 8] =
                make_int4(u[0] | (u[1] << 16), u[2] | (u[3] << 16),
                          u[4] | (u[5] << 16), u[6] | (u[7] << 16));
        }
        __syncthreads();
        const int cblk = ch * 2 + cc;
#pragma unroll
        for (int tap = 0; tap < 9; ++tap) {
            const int ky = tap / 3, kx = tap - 3 * (tap / 3);
            frag_ab a0 = *(const frag_ab*)(wA + (size_t)((tap * 8 + cblk) * 2) * 512 + l * 8);
            frag_ab a1 = *(const frag_ab*)(wA + (size_t)((tap * 8 + cblk) * 2 + 1) * 512 + l * 8);
#pragma unroll
            for (int q = 0; q < 2; ++q) {
                frag_ab bf = *(const frag_ab*)&xs[rw + ky][(pt0 + q) * 16 + li + kx][lg * 8];
                acc[0][q] = __builtin_amdgcn_mfma_f32_16x16x32_bf16(a0, bf, acc[0][q], 0, 0, 0);
                acc[1][q] = __builtin_amdgcn_mfma_f32_16x16x32_bf16(a1, bf, acc[1][q], 0, 0, 0);
            }
        }
    }

    const int h = h0 + rw;
#pragma unroll
    for (int mt = 0; mt < 2; ++mt)
#pragma unroll
        for (int j = 0; j < 4; ++j) {
            int m = mt * 16 + lg * 4 + j;
            if (m < 27) {
#pragma unroll
                for (int q = 0; q < 2; ++q) {
                    int pixel = (pt0 + q) * 16 + li;
                    part[((size_t)((ch * Bn + b) * 27 + m) << 12) + (h << 6) + pixel] =
                        acc[mt][q][j];
                }
            }
        }
}

// ---- Kernel 2b: per-k partial reduce + packed sampling metadata ------------
// mpack[q] = {i00|i01<<16, i10|i11<<16, half2(w00,w01), half2(w10,w11)}
__global__ __launch_bounds__(256) void metafin9(const float* __restrict__ part,
                                                int4* __restrict__ mpack) {
    const int k = blockIdx.y;
    const int idx = blockIdx.x * 256 + threadIdx.x;   // over Bn*HWn
    const int b = idx >> 12, p = idx & 4095;
    const int h = p >> 6, w = p & 63;

    float dy = 0.f, dx = 0.f, ms = 0.f;
#pragma unroll
    for (int ch = 0; ch < NCH; ++ch) {
        size_t base = ((size_t)((ch * Bn + b) * 27) << 12) + p;
        dy += part[base + ((size_t)(2 * k) << 12)];
        dx += part[base + ((size_t)(2 * k + 1) << 12)];
        ms += part[base + ((size_t)(18 + k) << 12)];
    }
    float m = 1.f / (1.f + expf(-ms));
    float yy = (float)(h + k / 3 - 1) + dy;
    float xx = (float)(w + k % 3 - 1) + dx;
    float y0f = floorf(yy), x0f = floorf(xx);
    float wy = yy - y0f, wx = xx - x0f;
    int y0 = (int)y0f, x0 = (int)x0f;
    int y1 = y0 + 1, x1 = x0 + 1;
    bool vy0 = (unsigned)y0 < (unsigned)Hn;
    bool vx0 = (unsigned)x0 < (unsigned)Wn;
    bool vy1 = (unsigned)y1 < (unsigned)Hn;
    bool vx1 = (unsigned)x1 < (unsigned)Wn;
    int cy0 = min(max(y0, 0), Hn - 1), cx0 = min(max(x0, 0), Wn - 1);
    int cy1 = min(max(y1, 0), Hn - 1), cx1 = min(max(x1, 0), Wn - 1);
    float w00 = (vy0 && vx0) ? (1.f - wy) * (1.f - wx) * m : 0.f;
    float w01 = (vy0 && vx1) ? (1.f - wy) * wx * m : 0.f;
    float w10 = (vy1 && vx0) ? wy * (1.f - wx) * m : 0.f;
    float w11 = (vy1 && vx1) ? wy * wx * m : 0.f;
    int i00 = (cy0 << 6) + cx0, i01 = (cy0 << 6) + cx1;
    int i10 = (cy1 << 6) + cx0, i11 = (cy1 << 6) + cx1;
    union { struct { __half a, bh; } h; int i; } pz, pw;
    pz.h.a = __float2half_rn(w00); pz.h.bh = __float2half_rn(w01);
    pw.h.a = __float2half_rn(w10); pw.h.bh = __float2half_rn(w11);
    int q = ((b * 9 + k) << 12) + p;
    mpack[q] = make_int4(i00 | (i01 << 16), i10 | (i11 << 16), pz.i, pw.i);
}

// ---- Kernel 3: fp16 MFMA deformable-conv GEMM, packed-half2 staging --------
// Grid (Bn, 64): blockIdx.x = batch so all 64 p-tile blocks of one batch land
// on one XCD (linear%8 == batch under round-robin) -> xh slice L2-resident.
__global__ __launch_bounds__(512, 4) void dconv(const __half2* __restrict__ xh,
                                                const ushort* __restrict__ wB,
                                                const int4* __restrict__ mpack,
                                                float* __restrict__ out) {
    __shared__ ushort sl[2][64][64];
    const int t = threadIdx.x;
    const int l = t & 63, w = t >> 6;
    const int li = l & 15, lg = l >> 4;
    const int hl = l >> 5;           // pixel parity within pair
    const int cl = l & 31;           // channel-dword lane
    const int b = blockIdx.x;
    const int p0 = blockIdx.y << 6;

    f32x4 acc[2][4];
#pragma unroll
    for (int a = 0; a < 2; ++a)
#pragma unroll
        for (int q = 0; q < 4; ++q) acc[a][q] = (f32x4)0.f;

    int4 m4[4];
    const __half2* xb = xh + (((size_t)b) << 19);   // b*4096*128

    auto LOADMETA = [&](int k) {
#pragma unroll
        for (int u = 0; u < 4; ++u) {
            int pix = w * 8 + 2 * u + hl;
            m4[u] = mpack[((b * 9 + k) << 12) + p0 + pix];
        }
    };

    auto STAGE = [&](int s, int buf) {
        const int ch = s & 3;
        const int co = ch * 32 + cl;
#pragma unroll
        for (int u = 0; u < 4; ++u) {
            int i00 = m4[u].x & 0xFFFF, i01 = ((unsigned)m4[u].x) >> 16;
            int i10 = m4[u].y & 0xFFFF, i11 = ((unsigned)m4[u].y) >> 16;
            union { int i; __half2 h; } uz, uw;
            uz.i = m4[u].z; uw.i = m4[u].w;
            __half2 v00 = xb[i00 * 128 + co];
            __half2 v01 = xb[i01 * 128 + co];
            __half2 v10 = xb[i10 * 128 + co];
            __half2 v11 = xb[i11 * 128 + co];
            __half2 sum = __hmul2(__half2half2(__low2half(uz.h)), v00);
            sum = __hfma2(__half2half2(__high2half(uz.h)), v01, sum);
            sum = __hfma2(__half2half2(__low2half(uw.h)), v10, sum);
            sum = __hfma2(__half2half2(__high2half(uw.h)), v11, sum);
            int pix = w * 8 + 2 * u + hl;
            int slot = (cl >> 2) ^ (pix & 7);
            *(__half2*)&sl[buf][pix][(slot << 3) + ((cl & 3) << 1)] = sum;
        }
    };

    auto COMPUTE = [&](int s, int buf) {
        const int k = s >> 2, ch = s & 3;
        const ushort* wp = wB + ((size_t)((k * 16 + 2 * w) * 512 + ch * 128)) * 8;
#pragma unroll
        for (int h = 0; h < 2; ++h) {
            frag_h bq[4];
#pragma unroll
            for (int pt = 0; pt < 4; ++pt)
                bq[pt] = *(const frag_h*)&sl[buf][pt * 16 + li]
                                           [((((h << 2) | lg) ^ (l & 7)) << 3)];
#pragma unroll
            for (int ft = 0; ft < 2; ++ft) {
                frag_h a = *(const frag_h*)(wp + (size_t)(ft * 512 + h * 64 + l) * 8);
#pragma unroll
                for (int pt = 0; pt < 4; ++pt)
                    acc[ft][pt] = __builtin_amdgcn_mfma_f32_16x16x32_f16(
                        a, bq[pt], acc[ft][pt], 0, 0, 0);
            }
        }
    };

    LOADMETA(0);
    STAGE(0, 0);
    __syncthreads();
#pragma unroll 1
    for (int s = 0; s < 36; ++s) {
        const int cur = s & 1;
        if (s + 1 < 36) {
            if (((s + 1) & 3) == 0) LOADMETA((s + 1) >> 2);
            STAGE(s + 1, cur ^ 1);
        }
        COMPUTE(s, cur);
        __syncthreads();
    }

    float* ob = out + (size_t)b * Fn * HWn + p0;
#pragma unroll
    for (int ft = 0; ft < 2; ++ft)
#pragma unroll
        for (int j = 0; j < 4; ++j) {
            int f = w * 32 + ft * 16 + lg * 4 + j;
#pragma unroll
            for (int pt = 0; pt < 4; ++pt)
                ob[(size_t)f * HWn + pt * 16 + li] = acc[ft][pt][j];
        }
}

extern "C" void kernel_launch(void* const* d_in, const int* in_sizes, int n_in,
                              void* d_out, int out_size, void* d_ws, size_t ws_size,
                              hipStream_t stream) {
    const float* x  = (const float*)d_in[0];
    const float* wo = (const float*)d_in[1];
    const float* wm = (const float*)d_in[2];
    const float* wd = (const float*)d_in[3];
    float* out = (float*)d_out;

    // ws: [mpack 4.72MB][region 18MB: part(14.16MB, dead after metafin9) then
    //      wB(1.18MB)+xh(16.78MB)][wA27 147KB]  => 23.74MB total (proven size)
    int4*    mpack = (int4*)d_ws;
    char*    region = (char*)d_ws + (size_t)NM * 16;
    float*   part  = (float*)region;
    ushort*  wBp   = (ushort*)region;
    __half2* xh    = (__half2*)(region + 1179648);
    ushort*  wA27  = (ushort*)(region + 18874368);

    wpack27<<<dim3(288), dim3(256), 0, stream>>>(wo, wm, wA27);
    offconv27<<<dim3(32, NCH, Bn), dim3(256), 0, stream>>>(x, wA27, part);
    metafin9<<<dim3(Bn * HWn / 256, 9), dim3(256), 0, stream>>>(part, mpack);
    wtrans2<<<dim3((Fn * Cn * Kn + 255) / 256), dim3(256), 0, stream>>>(wd, wBp);
    xpose<<<dim3(Bn * 4 * HWn / 256), dim3(256), 0, stream>>>(x, xh);
    dconv<<<dim3(Bn, HWn / 64), dim3(512), 0, stream>>>(xh, wBp, mpack, out);
}